// Round 12
// baseline (751.601 us; speedup 1.0000x reference)
//
#include <hip/hip_runtime.h>
#include <hip/hip_bf16.h>

// Problem constants
#define B_    16
#define T_    1000
#define FEAT  771
#define FEATP 800      // 771 padded to 25*32 (exact BK multiple -> guard-free GEMM)
#define H_    512
#define H3    1536
#define KN_   9
#define KHID  4608     // H*KN
#define M_    16000    // B*T
#define NOUT  257      // output column slice [257:514)

typedef _Float16 half8 __attribute__((ext_vector_type(8)));
typedef _Float16 half4 __attribute__((ext_vector_type(4)));
typedef _Float16 half2v __attribute__((ext_vector_type(2)));
typedef _Float16 h2 __attribute__((ext_vector_type(2)));
typedef float    floatx4 __attribute__((ext_vector_type(4)));

// tanh(z) = 1 - 2/(1+e^{2z})  — saturates correctly at +/-inf, no NaN
__device__ inline float tanh_fast(float z) {
    return 1.0f - 2.0f / (1.0f + __expf(2.0f * z));
}
__device__ inline float sigmoid_fast(float z) {
    return 1.0f / (1.0f + __expf(-z));
}

// async global->LDS, 16B per lane; LDS dst must be wave-uniform base
__device__ inline void gload16(const _Float16* g, _Float16* l) {
    __builtin_amdgcn_global_load_lds(
        (const __attribute__((address_space(1))) void*)g,
        (__attribute__((address_space(3))) void*)l, 16, 0, 0);
}

// Guaranteed packed fp16 ops; w is wave-uniform (SGPR src0).
__device__ inline void pk_fma_acc(unsigned& acc, unsigned w, unsigned x) {
    asm("v_pk_fma_f16 %0, %1, %2, %0" : "+v"(acc) : "s"(w), "v"(x));
}
__device__ inline unsigned pk_max(unsigned a, unsigned b) {
    unsigned d;
    asm("v_pk_max_f16 %0, %1, %2" : "=v"(d) : "v"(a), "v"(b));
    return d;
}

// ---------------------------------------------------------------------------
// fp32 -> fp16 convert of inputs, padding rows 771 -> 800 with zeros.
// Block 0 additionally packs ALL 324 conv weights (stride loop).
__global__ void convert_inputs(const float* __restrict__ in, _Float16* __restrict__ A1,
                               const float* __restrict__ ck, unsigned int* __restrict__ ckp) {
    if (blockIdx.x == 0) {
        for (int j = threadIdx.x; j < 9 * 36; j += 256) {
            const _Float16 w = (_Float16)ck[j];
            const unsigned short u = __builtin_bit_cast(unsigned short, w);
            ckp[j] = ((unsigned int)u << 16) | u;
        }
    }
    size_t i = (size_t)blockIdx.x * 256 + threadIdx.x;
    if (i >= (size_t)M_ * FEATP) return;
    size_t r = i / FEATP;
    int   cc = (int)(i % FEATP);
    A1[i] = (cc < FEAT) ? (_Float16)in[r * FEAT + cc] : (_Float16)0.f;
}

// ---------------------------------------------------------------------------
// LDS-tiled transpose+convert: Wt[n*Kp + kidx] = (k<K) ? W[k*ldw + coloff + n] : 0
// perm9: kidx = (k%9)*512 + k/9  (k-major planes for the conv output layout)
// blockIdx.z strides src by zsrc and dst by zdst (batched transposes).
__global__ __launch_bounds__(256) void transpose_w(
    const float* __restrict__ W, _Float16* __restrict__ Wt,
    int K, int N, int ldw, int coloff, int Kp, int perm9,
    size_t zsrc, size_t zdst)
{
    W  += (size_t)blockIdx.z * zsrc;
    Wt += (size_t)blockIdx.z * zdst;
    __shared__ float tile[32][33];
    const int kb = blockIdx.x * 32;
    const int nb = blockIdx.y * 32;
    const int tx = threadIdx.x & 31;
    const int ty = threadIdx.x >> 5;   // 0..7
    #pragma unroll
    for (int r = ty; r < 32; r += 8) {
        const int k = kb + r, n = nb + tx;
        tile[r][tx] = (k < K && n < N) ? W[(size_t)k * ldw + coloff + n] : 0.f;
    }
    __syncthreads();
    #pragma unroll
    for (int r = ty; r < 32; r += 8) {
        const int n = nb + r, k = kb + tx;
        if (n < N && k < Kp) {
            size_t kidx = (size_t)k;
            if (perm9) kidx = (size_t)(k % 9) * 512 + (size_t)(k / 9);
            Wt[(size_t)n * Kp + kidx] = (_Float16)tile[tx][r];
        }
    }
}

// ---------------------------------------------------------------------------
// Tiled fp16 MFMA GEMM: C[M x N] = A[M x Kp] * Bt[N x Kp]^T, fp32 accumulate.
// TM x 128 block tile, BK=32, 4 waves (2x2), (TM/32) x 4 frags of 16x16x32.
// 3-buffer COUNTED-vmcnt pipeline (T4): stage tile k+2, wait vmcnt(2*LPT)
// (tile k's loads — issued 2 iters ago — retired by FIFO; tiles k+1,k+2 stay
// in flight), barrier, compute k, barrier. Never drains vmcnt(0) mid-loop.
// RAG=1: ragged-N wave-uniform guards (G3's last n-tile: 1/128 cols live).
// EPI 0: tanh(+bias) -> fp16 Ch;  EPI 1: raw -> SoA U planes;
// EPI 2: FUSED FINAL: out = sigmoid(acc + bias[col]) * aux[row*FEAT+257+col]
template <int EPI, int RAG, int TM>
__global__ __launch_bounds__(256) void gemm_kernel(
    const _Float16* __restrict__ A, const _Float16* __restrict__ Bt,
    int Kp, int nk, int Nb,
    _Float16* __restrict__ Ch, float* __restrict__ Cf, int ldc,
    const float* __restrict__ bias, const float* __restrict__ aux)
{
    constexpr int MI   = TM / 32;   // fragment rows per wave (4 or 2)
    constexpr int ARPW = TM / 4;    // A rows staged per wave (32 or 16)
    __shared__ __align__(16) _Float16 As[3][TM][32];
    __shared__ __align__(16) _Float16 Bs[3][128][32];

    const int tid  = threadIdx.x;
    const int m0   = blockIdx.x * TM;
    const int n0   = blockIdx.y * 128;
    const int koff = blockIdx.z * (nk << 5);   // K-slice origin (0 when gridDim.z==1)
    const int wave = tid >> 6;
    const int lane = tid & 63;
    const int wr   = (wave >> 1) * (TM / 2);   // wave row offset
    const int wc   = (wave & 1) << 6;          // wave col offset (0/64)
    const int lrow = lane & 15;
    const int lq   = lane >> 4;                // 0..3
    const bool waveAlive = !RAG || (n0 + wc < Nb);

    // staging: wave w stages A rows [w*ARPW, +ARPW), B rows [w*32, +32)
    const int srowA  = wave * ARPW + (lane >> 2);
    const int srowB  = wave * 32   + (lane >> 2);
    const int schunk = (lane & 3) * 8;            // halves within row
    const _Float16* aSrc = A  + (size_t)(m0 + srowA) * Kp + koff + schunk;
    const _Float16* bSrc = Bt + (size_t)(n0 + srowB) * Kp + koff + schunk;
    const size_t rstep = (size_t)16 * Kp;

    floatx4 acc[MI][4];
    #pragma unroll
    for (int i = 0; i < MI; ++i)
        #pragma unroll
        for (int j = 0; j < 4; ++j)
            #pragma unroll
            for (int r = 0; r < 4; ++r) acc[i][j][r] = 0.f;

    auto stage = [&](int buf, int kc2) {
        const _Float16* a2 = aSrc + (size_t)kc2 * 32;
        const _Float16* b2 = bSrc + (size_t)kc2 * 32;
        gload16(a2, &As[buf][wave * ARPW][0]);
        if constexpr (TM == 128) gload16(a2 + rstep, &As[buf][wave * ARPW + 16][0]);
        gload16(b2,         &Bs[buf][wave * 32][0]);
        gload16(b2 + rstep, &Bs[buf][wave * 32 + 16][0]);
    };

    // prologue: stage tiles 0 and 1
    stage(0, 0);
    if (nk > 1) stage(1, 1);

    int cur = 0;
    for (int kc = 0; kc < nk; ++kc) {
        if (kc + 2 < nk) {
            int pre = cur + 2; if (pre >= 3) pre -= 3;
            stage(pre, kc + 2);
            if constexpr (TM == 128) asm volatile("s_waitcnt vmcnt(8)" ::: "memory");
            else                     asm volatile("s_waitcnt vmcnt(6)" ::: "memory");
        } else if (kc + 1 < nk) {
            if constexpr (TM == 128) asm volatile("s_waitcnt vmcnt(4)" ::: "memory");
            else                     asm volatile("s_waitcnt vmcnt(3)" ::: "memory");
        } else {
            asm volatile("s_waitcnt vmcnt(0)" ::: "memory");
        }
        __builtin_amdgcn_s_barrier();   // all waves' tile-kc loads landed

        if (waveAlive) {
            half8 af[MI], bfr[4];
            #pragma unroll
            for (int i = 0; i < MI; ++i) af[i] = *(const half8*)(&As[cur][wr + i * 16 + lrow][lq * 8]);
            #pragma unroll
            for (int j = 0; j < 4; ++j) {
                if (RAG && n0 + wc + j * 16 >= Nb) continue;
                bfr[j] = *(const half8*)(&Bs[cur][wc + j * 16 + lrow][lq * 8]);
            }
            #pragma unroll
            for (int i = 0; i < MI; ++i)
                #pragma unroll
                for (int j = 0; j < 4; ++j) {
                    if (RAG && n0 + wc + j * 16 >= Nb) continue;
                    acc[i][j] = __builtin_amdgcn_mfma_f32_16x16x32_f16(af[i], bfr[j], acc[i][j], 0, 0, 0);
                }
        }

        __builtin_amdgcn_s_barrier();   // reads done before buffer reuse
        cur = (cur == 2) ? 0 : cur + 1;
    }

    // Epilogue: C/D layout col=lane&15, row=quad*4+reg
    #pragma unroll
    for (int j = 0; j < 4; ++j) {
        const int col = n0 + wc + j * 16 + lrow;
        if (col >= Nb) continue;
        #pragma unroll
        for (int i = 0; i < MI; ++i) {
            #pragma unroll
            for (int r = 0; r < 4; ++r) {
                const int row = m0 + wr + i * 16 + lq * 4 + r;
                float v = acc[i][j][r];
                if constexpr (EPI == 0) {
                    float z = v + bias[col];
                    Ch[(size_t)row * ldc + col] = (_Float16)tanh_fast(z);
                } else if constexpr (EPI == 1) {
                    Ch[(size_t)(col >> 9) * ((size_t)M_ * 512) + (size_t)row * 512 + (col & 511)] = (_Float16)v;
                } else {
                    // fused final epilogue: sigmoid(acc+bias) * center-frame input
                    const float a = aux[(size_t)row * FEAT + 257 + col];
                    Cf[(size_t)row * NOUT + col] = sigmoid_fast(v + bias[col]) * a;
                }
            }
        }
    }
}

// ---------------------------------------------------------------------------
// SRU scan reading SoA U planes + X directly via LDS double-buffer staging.
// Each 40-step buffer staged with exactly 20 global_load_lds; double-buffered;
// counted vmcnt(20) keeps next buffer's loads in flight under the compute.
__global__ __launch_bounds__(64) void sru_scan(
    const _Float16* __restrict__ U,   // 3 planes [M][512] (xt, fp, rp)
    const _Float16* __restrict__ X,   // [M][512] layer input
    _Float16* __restrict__ Xout,
    const float* __restrict__ v, const float* __restrict__ bg)
{
    __shared__ __align__(16) _Float16 lds[2][4][40][64];   // 40 KiB
    const int tid = threadIdx.x;
    const int b   = blockIdx.x >> 3;
    const int h0  = (blockIdx.x & 7) << 6;
    const int h   = h0 + tid;
    const float vf = v[h],       vr = v[512 + h];
    const float bf = bg[h],      br = bg[512 + h];

    const _Float16* plane0 = U;
    const _Float16* plane1 = U + (size_t)M_ * 512;
    const _Float16* plane2 = U + 2 * (size_t)M_ * 512;
    const _Float16* plane3 = X;

    const int lrow = tid >> 3;        // 0..7: t sub-row within a 1KB chunk
    const int lcol = (tid & 7) * 8;   // halves within row (16 B per lane)

    _Float16* ox = Xout + (size_t)b * T_ * 512 + h;

    // refill buffer bufi with t-rows [t0, t0+40)
    auto refill = [&](int bufi, int t0) {
        const size_t rbase = (size_t)(b * T_ + t0 + lrow) * 512 + h0 + lcol;
        #pragma unroll
        for (int j = 0; j < 5; ++j) {
            const size_t o = rbase + (size_t)(8 * j) * 512;
            gload16(plane0 + o, &lds[bufi][0][8 * j][0]);
            gload16(plane1 + o, &lds[bufi][1][8 * j][0]);
            gload16(plane2 + o, &lds[bufi][2][8 * j][0]);
            gload16(plane3 + o, &lds[bufi][3][8 * j][0]);
        }
    };

    refill(0, 0);
    float c = 0.f;
    int cur = 0;
    for (int tb = 0; tb < 25; ++tb) {
        const int t0 = tb * 40;
        if (tb + 1 < 25) {
            refill(cur ^ 1, t0 + 40);
            asm volatile("s_waitcnt vmcnt(20)" ::: "memory");
        } else {
            asm volatile("s_waitcnt vmcnt(0)" ::: "memory");
        }
        __builtin_amdgcn_sched_barrier(0);
        #pragma unroll
        for (int j = 0; j < 40; ++j) {
            const float xt = (float)lds[cur][0][j][tid];
            const float fp = (float)lds[cur][1][j][tid];
            const float rp = (float)lds[cur][2][j][tid];
            const float x  = (float)lds[cur][3][j][tid];
            const float f  = sigmoid_fast(fp + vf * c + bf);
            const float r  = sigmoid_fast(rp + vr * c + br);
            const float cn = f * c + (1.0f - f) * xt;
            const float hO = r * cn + (1.0f - r) * x;
            ox[(size_t)(t0 + j) * 512] = (_Float16)hO;
            c = cn;
        }
        cur ^= 1;
    }
}

// ---------------------------------------------------------------------------
// Fused conv6x6(asym pad 3,2) + maxpool3x3(pad 1) + bias + tanh.
// EXACT r8 structure (best measured: 134.5 µs) — 320 threads, packed fp16
// inline asm, vertical-first pool, tanh after pool, k-major output.
#define CVW 76   // cv row width (halves)

__global__ __launch_bounds__(320) void conv_pool(
    const _Float16* __restrict__ X, const unsigned int* __restrict__ ckp,
    const float* __restrict__ cb, _Float16* __restrict__ A3)
{
    __shared__ __align__(16) _Float16 in_s[23][80];       // fp16, rows padded to 80
    __shared__ __align__(16) _Float16 cv[9][18][CVW];     // raw conv fp16; -65504 = outside
    const int tid = threadIdx.x;
    int bi = blockIdx.x;
    const int th = bi & 7;  bi >>= 3;
    const int tt = bi % 63;
    const int b  = bi / 63;
    const int t0 = tt * 16, h0 = th * 64;

    for (int i = tid; i < 23 * 76; i += 320) {
        const int r = i / 76, cc = i % 76;
        const int gt = t0 - 4 + r, gh = h0 - 4 + cc;
        _Float16 val = (_Float16)0.f;   // conv zero-padding
        if (gt >= 0 && gt < T_ && gh >= 0 && gh < H_)
            val = X[((size_t)b * T_ + gt) * H_ + gh];
        in_s[r][cc] = val;
    }
    __syncthreads();

    // conv phase: 18 pt x 17 ph-groups = 306 tasks, one per thread
    if (tid < 306) {
        const int pt = tid / 17;        // conv row: ct = t0 - 1 + pt
        const int co = (tid % 17) * 4;  // conv col offset (co % 4 == 0)

        const int ct = t0 - 1 + pt;
        const bool rok = (ct >= 0) && (ct < T_);
        const int chb = h0 - 1 + co;
        const bool ok0 = rok && (chb + 0 >= 0) && (chb + 0 < H_);
        const bool ok1 = rok && (chb + 1 >= 0) && (chb + 1 < H_);
        const bool ok2 = rok && (chb + 2 >= 0) && (chb + 2 < H_);
        const bool ok3 = rok && (chb + 3 >= 0) && (chb + 3 < H_);

        unsigned acc0[9], acc1[9];      // packed (q0,q1) and (q2,q3), fp16 pairs
        #pragma unroll
        for (int k = 0; k < 9; ++k) { acc0[k] = 0u; acc1[k] = 0u; }

        #pragma unroll 1
        for (int ii = 0; ii < 6; ++ii) {
            const unsigned int* rw = (const unsigned int*)&in_s[pt + ii][co];  // 8-B aligned
            const uint2 a01 = *(const uint2*)(rw);
            const uint2 a23 = *(const uint2*)(rw + 2);
            const unsigned int A0 = a01.x, A1v = a01.y, A2 = a23.x, A3v = a23.y;
            const unsigned int A4 = rw[4];
            // misaligned pairs (1 instr each): M[i] = halves(co+2i+1, co+2i+2)
            const unsigned int M0 = __builtin_amdgcn_alignbit(A1v, A0, 16);
            const unsigned int M1 = __builtin_amdgcn_alignbit(A2, A1v, 16);
            const unsigned int M2 = __builtin_amdgcn_alignbit(A3v, A2, 16);
            const unsigned int M3 = __builtin_amdgcn_alignbit(A4, A3v, 16);

            const unsigned int* wt = ckp + ii * 6;   // + k*36 + J, wave-uniform (SGPR)
            #pragma unroll
            for (int k = 0; k < 9; ++k) {
                const unsigned int* wk = wt + k * 36;
                pk_fma_acc(acc0[k], wk[0], A0);   pk_fma_acc(acc1[k], wk[0], A1v);  // J=0
                pk_fma_acc(acc0[k], wk[1], M0);   pk_fma_acc(acc1[k], wk[1], M1);   // J=1
                pk_fma_acc(acc0[k], wk[2], A1v);  pk_fma_acc(acc1[k], wk[2], A2);   // J=2
                pk_fma_acc(acc0[k], wk[3], M1);   pk_fma_acc(acc1[k], wk[3], M2);   // J=3
                pk_fma_acc(acc0[k], wk[4], A2);   pk_fma_acc(acc1[k], wk[4], A3v);  // J=4
                pk_fma_acc(acc0[k], wk[5], M2);   pk_fma_acc(acc1[k], wk[5], M3);   // J=5
            }
        }

        const _Float16 NEG = (_Float16)(-65504.f);
        #pragma unroll
        for (int k = 0; k < 9; ++k) {
            const h2 pa = __builtin_bit_cast(h2, acc0[k]);
            const h2 pb = __builtin_bit_cast(h2, acc1[k]);
            half4 o;
            o[0] = ok0 ? pa[0] : NEG;
            o[1] = ok1 ? pa[1] : NEG;
            o[2] = ok2 ? pb[0] : NEG;
            o[3] = ok3 ? pb[1] : NEG;
            *(half4*)(&cv[k][pt][co]) = o;
        }
    }
    __syncthreads();

    // pool phase: 16 pt x 16 ph-groups of 4 = 256 tasks; vertical-first packed
    // max, then horizontal; bias+tanh in fp32 on the 4 pooled values only.
    if (tid < 256) {
        const int pt = tid >> 4;
        const int gt = t0 + pt;
        if (gt < T_) {
            const int ph = (tid & 15) * 4;
            _Float16* dst = A3 + ((size_t)b * T_ + gt) * KHID + (h0 + ph);
            #pragma unroll
            for (int k = 0; k < 9; ++k) {
                const unsigned* c0 = (const unsigned*)&cv[k][pt + 0][ph];
                const unsigned* c1 = (const unsigned*)&cv[k][pt + 1][ph];
                const unsigned* c2 = (const unsigned*)&cv[k][pt + 2][ph];
                const uint2 x0 = *(const uint2*)c0;  const unsigned y0 = c0[2];
                const uint2 x1 = *(const uint2*)c1;  const unsigned y1 = c1[2];
                const uint2 x2 = *(const uint2*)c2;  const unsigned y2 = c2[2];
                // vertical max (element-wise over 3 rows)
                const unsigned VA = pk_max(pk_max(x0.x, x1.x), x2.x);  // (u0,u1)
                const unsigned VB = pk_max(pk_max(x0.y, x1.y), x2.y);  // (u2,u3)
                const unsigned VC = pk_max(pk_max(y0,   y1),   y2);    // (u4,u5)
                // horizontal 3-window max on the vertical result
                const unsigned m12 = __builtin_amdgcn_alignbit(VB, VA, 16);  // (u1,u2)
                const unsigned m34 = __builtin_amdgcn_alignbit(VC, VB, 16);  // (u3,u4)
                const unsigned q01 = pk_max(pk_max(VA, m12), VB);
                const unsigned q23 = pk_max(pk_max(VB, m34), VC);
                const h2 qa = __builtin_bit_cast(h2, q01);
                const h2 qb = __builtin_bit_cast(h2, q23);
                const float bk = cb[k];
                half4 o;
                o[0] = (_Float16)tanh_fast((float)qa[0] + bk);
                o[1] = (_Float16)tanh_fast((float)qa[1] + bk);
                o[2] = (_Float16)tanh_fast((float)qb[0] + bk);
                o[3] = (_Float16)tanh_fast((float)qb[1] + bk);
                *(half4*)(dst + (size_t)k * 512) = o;
            }
        }
    }
}

// ---------------------------------------------------------------------------
extern "C" void kernel_launch(void* const* d_in, const int* in_sizes, int n_in,
                              void* d_out, int out_size, void* d_ws, size_t ws_size,
                              hipStream_t stream) {
    const float* inputs = (const float*)d_in[0];
    const float* W_in   = (const float*)d_in[1];
    const float* b_in   = (const float*)d_in[2];
    const float* W_rnn  = (const float*)d_in[3];
    const float* v_rnn  = (const float*)d_in[4];
    const float* b_rnn  = (const float*)d_in[5];
    const float* conv_k = (const float*)d_in[6];
    const float* conv_b = (const float*)d_in[7];
    const float* W_out  = (const float*)d_in[8];
    const float* b_out  = (const float*)d_in[9];
    float* out = (float*)d_out;

    char* ws = (char*)d_ws;
    size_t off = 0;
    auto take = [&](size_t bytes) -> char* {
        off = (off + 255) & ~(size_t)255;
        char* p = ws + off;
        off += bytes;
        return p;
    };
    _Float16* W3T  = (_Float16*)take((size_t)NOUT * KHID * 2);  // W_out[:,257:514)^T, K-permuted
    _Float16* A1   = (_Float16*)take((size_t)M_ * FEATP * 2);   // inputs fp16, padded (dead after G1)
    _Float16* W1T  = (_Float16*)take((size_t)H_ * FEATP * 2);   // W_in^T
    _Float16* W2T0 = (_Float16*)take((size_t)H3 * H_ * 2);      // W_rnn[0]^T
    _Float16* W2T1 = (_Float16*)take((size_t)H3 * H_ * 2);      // W_rnn[1]^T (contiguous after W2T0)
    _Float16* X0   = (_Float16*)take((size_t)M_ * H_ * 2);      // tanh(G1); scan1 output (X2)
    _Float16* X1   = (_Float16*)take((size_t)M_ * H_ * 2);      // scan0 output
    _Float16* U    = (_Float16*)take(3 * (size_t)M_ * 512 * 2); // SoA U planes (xt,fp,rp)
    _Float16* A3   = (_Float16*)take((size_t)M_ * KHID * 2);    // pooled conv, k-major (k*512+h)
    unsigned int* ckp = (unsigned int*)take(9 * 36 * 4);        // packed dup'd fp16 conv weights
    _Float16* X2 = X0;  // X0 dead after G2-layer0+scan0 -> reuse for scan1 output

    // --- weight/input preprocessing (fp32 -> fp16, transpose to NxK) ---
    {
        size_t n = (size_t)M_ * FEATP;
        convert_inputs<<<dim3((unsigned)((n + 255) / 256)), 256, 0, stream>>>(inputs, A1, conv_k, ckp);
    }
    transpose_w<<<dim3(25, 16), 256, 0, stream>>>(W_in, W1T, FEAT, H_, H_, 0, FEATP, 0, 0, 0);
    transpose_w<<<dim3(16, 48, 2), 256, 0, stream>>>(W_rnn, W2T0, H_, H3, H3, 0, H_, 0,
                                                     (size_t)H_ * H3, (size_t)H3 * H_);
    transpose_w<<<dim3(144, 9), 256, 0, stream>>>(W_out, W3T, KHID, NOUT, FEAT, 257, KHID, 1, 0, 0);

    // --- G1: X0 = tanh(inputs @ W_in + b_in) ---
    gemm_kernel<0, 0, 128><<<dim3(125, 4), 256, 0, stream>>>(A1, W1T, FEATP, 25, H_, X0, nullptr, H_, b_in, nullptr);

    // --- SRU layer 0: U-GEMM (SoA) -> LDS-staged scan (reads planes directly) ---
    gemm_kernel<1, 0, 128><<<dim3(125, 12), 256, 0, stream>>>(X0, W2T0, H_, 16, H3, U, nullptr, 0, nullptr, nullptr);
    sru_scan<<<dim3(128), 64, 0, stream>>>(U, X0, X1, v_rnn, b_rnn);

    // --- SRU layer 1 ---
    gemm_kernel<1, 0, 128><<<dim3(125, 12), 256, 0, stream>>>(X1, W2T1, H_, 16, H3, U, nullptr, 0, nullptr, nullptr);
    sru_scan<<<dim3(128), 64, 0, stream>>>(U, X1, X2, v_rnn + 1024, b_rnn + 1024);

    // --- conv + maxpool + bias + tanh fused, producing final-GEMM A matrix ---
    conv_pool<<<dim3(16 * 63 * 8), 320, 0, stream>>>(X2, ckp, conv_b, A3);

    // --- G3 fused final, TM=128 + counted-vmcnt pipeline: out = sigmoid(A3@W3T + b) * inputs-center ---
    gemm_kernel<2, 1, 128><<<dim3(125, 3), 256, 0, stream>>>(A3, W3T, KHID, 144, NOUT, nullptr, out, 0, b_out + 257, inputs);
}

// Round 13
// 703.925 us; speedup vs baseline: 1.0677x; 1.0677x over previous
//
#include <hip/hip_runtime.h>
#include <hip/hip_bf16.h>

// Problem constants
#define B_    16
#define T_    1000
#define FEAT  771
#define FEATP 800      // 771 padded to 25*32 (exact BK multiple -> guard-free GEMM)
#define H_    512
#define H3    1536
#define KN_   9
#define KHID  4608     // H*KN
#define M_    16000    // B*T
#define NOUT  257      // output column slice [257:514)
#define KSLICES 4      // split-K factor for the final GEMM (width > fusion: r10-r12)

typedef _Float16 half8 __attribute__((ext_vector_type(8)));
typedef _Float16 half4 __attribute__((ext_vector_type(4)));
typedef _Float16 half2v __attribute__((ext_vector_type(2)));
typedef _Float16 h2 __attribute__((ext_vector_type(2)));
typedef float    floatx4 __attribute__((ext_vector_type(4)));

// tanh(z) = 1 - 2/(1+e^{2z})  — saturates correctly at +/-inf, no NaN
__device__ inline float tanh_fast(float z) {
    return 1.0f - 2.0f / (1.0f + __expf(2.0f * z));
}
__device__ inline float sigmoid_fast(float z) {
    return 1.0f / (1.0f + __expf(-z));
}

// async global->LDS, 16B per lane; LDS dst must be wave-uniform base
__device__ inline void gload16(const _Float16* g, _Float16* l) {
    __builtin_amdgcn_global_load_lds(
        (const __attribute__((address_space(1))) void*)g,
        (__attribute__((address_space(3))) void*)l, 16, 0, 0);
}

// Guaranteed packed fp16 ops; w is wave-uniform (SGPR src0).
__device__ inline void pk_fma_acc(unsigned& acc, unsigned w, unsigned x) {
    asm("v_pk_fma_f16 %0, %1, %2, %0" : "+v"(acc) : "s"(w), "v"(x));
}
__device__ inline unsigned pk_max(unsigned a, unsigned b) {
    unsigned d;
    asm("v_pk_max_f16 %0, %1, %2" : "=v"(d) : "v"(a), "v"(b));
    return d;
}

// ---------------------------------------------------------------------------
// fp32 -> fp16 convert of inputs, padding rows 771 -> 800 with zeros.
// Block 0 additionally packs ALL 324 conv weights (stride loop).
__global__ void convert_inputs(const float* __restrict__ in, _Float16* __restrict__ A1,
                               const float* __restrict__ ck, unsigned int* __restrict__ ckp) {
    if (blockIdx.x == 0) {
        for (int j = threadIdx.x; j < 9 * 36; j += 256) {
            const _Float16 w = (_Float16)ck[j];
            const unsigned short u = __builtin_bit_cast(unsigned short, w);
            ckp[j] = ((unsigned int)u << 16) | u;
        }
    }
    size_t i = (size_t)blockIdx.x * 256 + threadIdx.x;
    if (i >= (size_t)M_ * FEATP) return;
    size_t r = i / FEATP;
    int   cc = (int)(i % FEATP);
    A1[i] = (cc < FEAT) ? (_Float16)in[r * FEAT + cc] : (_Float16)0.f;
}

// ---------------------------------------------------------------------------
// LDS-tiled transpose+convert: Wt[n*Kp + kidx] = (k<K) ? W[k*ldw + coloff + n] : 0
// perm9: kidx = (k%9)*512 + k/9  (k-major planes for the conv output layout)
// blockIdx.z strides src by zsrc and dst by zdst (batched transposes).
__global__ __launch_bounds__(256) void transpose_w(
    const float* __restrict__ W, _Float16* __restrict__ Wt,
    int K, int N, int ldw, int coloff, int Kp, int perm9,
    size_t zsrc, size_t zdst)
{
    W  += (size_t)blockIdx.z * zsrc;
    Wt += (size_t)blockIdx.z * zdst;
    __shared__ float tile[32][33];
    const int kb = blockIdx.x * 32;
    const int nb = blockIdx.y * 32;
    const int tx = threadIdx.x & 31;
    const int ty = threadIdx.x >> 5;   // 0..7
    #pragma unroll
    for (int r = ty; r < 32; r += 8) {
        const int k = kb + r, n = nb + tx;
        tile[r][tx] = (k < K && n < N) ? W[(size_t)k * ldw + coloff + n] : 0.f;
    }
    __syncthreads();
    #pragma unroll
    for (int r = ty; r < 32; r += 8) {
        const int n = nb + r, k = kb + tx;
        if (n < N && k < Kp) {
            size_t kidx = (size_t)k;
            if (perm9) kidx = (size_t)(k % 9) * 512 + (size_t)(k / 9);
            Wt[(size_t)n * Kp + kidx] = (_Float16)tile[tx][r];
        }
    }
}

// ---------------------------------------------------------------------------
// Tiled fp16 MFMA GEMM: C[M x N] = A[M x Kp] * Bt[N x Kp]^T, fp32 accumulate.
// 128x128 block tile, BK=32, 4 waves (2x2), each wave 4x4 of 16x16x32 MFMA.
// 2-phase prefetch: double-buffered LDS, tile k+1 staged via global_load_lds
// BEFORE computing tile k; one vmcnt(0)+raw-barrier per K-step.
// RAG=1: ragged-N wave-uniform guards (G3's last n-tile: 1/128 cols live).
template <int EPI, int RAG>
__global__ __launch_bounds__(256) void gemm_kernel(
    const _Float16* __restrict__ A, const _Float16* __restrict__ Bt,
    int Kp, int nk, int Nb,
    _Float16* __restrict__ Ch, float* __restrict__ Cf, int ldc,
    const float* __restrict__ bias)
{
    __shared__ __align__(16) _Float16 As[2][128][32];
    __shared__ __align__(16) _Float16 Bs[2][128][32];

    const int tid  = threadIdx.x;
    const int m0   = blockIdx.x * 128;
    const int n0   = blockIdx.y * 128;
    const int koff = blockIdx.z * (nk << 5);   // K-slice origin
    const int wave = tid >> 6;
    const int lane = tid & 63;
    const int wr   = (wave >> 1) << 6;   // wave row offset (0/64)
    const int wc   = (wave & 1) << 6;    // wave col offset (0/64)
    const int lrow = lane & 15;
    const int lq   = lane >> 4;          // 0..3
    const bool waveAlive = !RAG || (n0 + wc < Nb);

    // staging: wave w stages rows [w*32, w*32+32), 2 instrs per matrix
    const int srow0  = wave * 32 + (lane >> 2);   // rows for instr 0
    const int schunk = (lane & 3) * 8;            // halves within row
    const _Float16* aSrc = A  + (size_t)(m0 + srow0) * Kp + koff + schunk;
    const _Float16* bSrc = Bt + (size_t)(n0 + srow0) * Kp + koff + schunk;
    const size_t rstep = (size_t)16 * Kp;

    floatx4 acc[4][4];
    #pragma unroll
    for (int i = 0; i < 4; ++i)
        #pragma unroll
        for (int j = 0; j < 4; ++j)
            #pragma unroll
            for (int r = 0; r < 4; ++r) acc[i][j][r] = 0.f;

    // prologue: stage tile 0 into buffer 0
    gload16(aSrc,         &As[0][wave * 32][0]);
    gload16(aSrc + rstep, &As[0][wave * 32 + 16][0]);
    gload16(bSrc,         &Bs[0][wave * 32][0]);
    gload16(bSrc + rstep, &Bs[0][wave * 32 + 16][0]);
    asm volatile("s_waitcnt vmcnt(0)" ::: "memory");
    __builtin_amdgcn_s_barrier();

    for (int kc = 0; kc < nk; ++kc) {
        const int cur = kc & 1;
        if (kc + 1 < nk) {   // prefetch next tile into the other buffer
            const _Float16* a2 = aSrc + (size_t)(kc + 1) * 32;
            const _Float16* b2 = bSrc + (size_t)(kc + 1) * 32;
            gload16(a2,         &As[cur ^ 1][wave * 32][0]);
            gload16(a2 + rstep, &As[cur ^ 1][wave * 32 + 16][0]);
            gload16(b2,         &Bs[cur ^ 1][wave * 32][0]);
            gload16(b2 + rstep, &Bs[cur ^ 1][wave * 32 + 16][0]);
        }

        if (waveAlive) {
            half8 af[4], bfr[4];
            #pragma unroll
            for (int i = 0; i < 4; ++i) af[i] = *(const half8*)(&As[cur][wr + i * 16 + lrow][lq * 8]);
            #pragma unroll
            for (int j = 0; j < 4; ++j) {
                if (RAG && n0 + wc + j * 16 >= Nb) continue;
                bfr[j] = *(const half8*)(&Bs[cur][wc + j * 16 + lrow][lq * 8]);
            }
            #pragma unroll
            for (int i = 0; i < 4; ++i)
                #pragma unroll
                for (int j = 0; j < 4; ++j) {
                    if (RAG && n0 + wc + j * 16 >= Nb) continue;
                    acc[i][j] = __builtin_amdgcn_mfma_f32_16x16x32_f16(af[i], bfr[j], acc[i][j], 0, 0, 0);
                }
        }

        if (kc + 1 < nk) {
            asm volatile("s_waitcnt vmcnt(0)" ::: "memory");
            __builtin_amdgcn_s_barrier();
        }
    }

    // Epilogue: C/D layout col=lane&15, row=quad*4+reg
    #pragma unroll
    for (int j = 0; j < 4; ++j) {
        const int col = n0 + wc + j * 16 + lrow;
        if (col >= Nb) continue;
        #pragma unroll
        for (int i = 0; i < 4; ++i) {
            #pragma unroll
            for (int r = 0; r < 4; ++r) {
                const int row = m0 + wr + i * 16 + lq * 4 + r;
                float v = acc[i][j][r];
                if constexpr (EPI == 0) {
                    float z = v + bias[col];
                    Ch[(size_t)row * ldc + col] = (_Float16)tanh_fast(z);
                } else if constexpr (EPI == 1) {
                    Ch[(size_t)(col >> 9) * ((size_t)M_ * 512) + (size_t)row * 512 + (col & 511)] = (_Float16)v;
                } else {
                    Cf[(size_t)blockIdx.z * M_ * NOUT + (size_t)row * NOUT + col] = v;
                }
            }
        }
    }
}

// ---------------------------------------------------------------------------
// Split-K reduction + sigmoid epilogue for the final GEMM (KSLICES=4).
__global__ __launch_bounds__(256) void reduce_out(
    const float* __restrict__ Cp, const float* __restrict__ bias,
    const float* __restrict__ aux, float* __restrict__ out)
{
    const size_t i = (size_t)blockIdx.x * 256 + threadIdx.x;
    if (i >= (size_t)M_ * NOUT) return;
    const int row = (int)(i / NOUT);
    const int col = (int)(i % NOUT);
    float s = Cp[i] + Cp[i + (size_t)M_ * NOUT]
            + Cp[i + 2 * (size_t)M_ * NOUT] + Cp[i + 3 * (size_t)M_ * NOUT];
    out[i] = sigmoid_fast(s + bias[col]) * aux[(size_t)row * FEAT + 257 + col];
}

// ---------------------------------------------------------------------------
// SRU scan reading SoA U planes + X directly via LDS double-buffer staging.
// Each 40-step buffer staged with exactly 20 global_load_lds; double-buffered;
// counted vmcnt(20) keeps next buffer's loads in flight under the compute.
__global__ __launch_bounds__(64) void sru_scan(
    const _Float16* __restrict__ U,   // 3 planes [M][512] (xt, fp, rp)
    const _Float16* __restrict__ X,   // [M][512] layer input
    _Float16* __restrict__ Xout,
    const float* __restrict__ v, const float* __restrict__ bg)
{
    __shared__ __align__(16) _Float16 lds[2][4][40][64];   // 40 KiB
    const int tid = threadIdx.x;
    const int b   = blockIdx.x >> 3;
    const int h0  = (blockIdx.x & 7) << 6;
    const int h   = h0 + tid;
    const float vf = v[h],       vr = v[512 + h];
    const float bf = bg[h],      br = bg[512 + h];

    const _Float16* plane0 = U;
    const _Float16* plane1 = U + (size_t)M_ * 512;
    const _Float16* plane2 = U + 2 * (size_t)M_ * 512;
    const _Float16* plane3 = X;

    const int lrow = tid >> 3;        // 0..7: t sub-row within a 1KB chunk
    const int lcol = (tid & 7) * 8;   // halves within row (16 B per lane)

    _Float16* ox = Xout + (size_t)b * T_ * 512 + h;

    // refill buffer bufi with t-rows [t0, t0+40)
    auto refill = [&](int bufi, int t0) {
        const size_t rbase = (size_t)(b * T_ + t0 + lrow) * 512 + h0 + lcol;
        #pragma unroll
        for (int j = 0; j < 5; ++j) {
            const size_t o = rbase + (size_t)(8 * j) * 512;
            gload16(plane0 + o, &lds[bufi][0][8 * j][0]);
            gload16(plane1 + o, &lds[bufi][1][8 * j][0]);
            gload16(plane2 + o, &lds[bufi][2][8 * j][0]);
            gload16(plane3 + o, &lds[bufi][3][8 * j][0]);
        }
    };

    refill(0, 0);
    float c = 0.f;
    int cur = 0;
    for (int tb = 0; tb < 25; ++tb) {
        const int t0 = tb * 40;
        if (tb + 1 < 25) {
            refill(cur ^ 1, t0 + 40);
            asm volatile("s_waitcnt vmcnt(20)" ::: "memory");
        } else {
            asm volatile("s_waitcnt vmcnt(0)" ::: "memory");
        }
        __builtin_amdgcn_sched_barrier(0);
        #pragma unroll
        for (int j = 0; j < 40; ++j) {
            const float xt = (float)lds[cur][0][j][tid];
            const float fp = (float)lds[cur][1][j][tid];
            const float rp = (float)lds[cur][2][j][tid];
            const float x  = (float)lds[cur][3][j][tid];
            const float f  = sigmoid_fast(fp + vf * c + bf);
            const float r  = sigmoid_fast(rp + vr * c + br);
            const float cn = f * c + (1.0f - f) * xt;
            const float hO = r * cn + (1.0f - r) * x;
            ox[(size_t)(t0 + j) * 512] = (_Float16)hO;
            c = cn;
        }
        cur ^= 1;
    }
}

// ---------------------------------------------------------------------------
// Fused conv6x6(asym pad 3,2) + maxpool3x3(pad 1) + bias + tanh.
// EXACT r8 structure (best measured: 134.5 µs) — 320 threads, packed fp16
// inline asm, vertical-first pool, tanh after pool, k-major output.
#define CVW 76   // cv row width (halves)

__global__ __launch_bounds__(320) void conv_pool(
    const _Float16* __restrict__ X, const unsigned int* __restrict__ ckp,
    const float* __restrict__ cb, _Float16* __restrict__ A3)
{
    __shared__ __align__(16) _Float16 in_s[23][80];       // fp16, rows padded to 80
    __shared__ __align__(16) _Float16 cv[9][18][CVW];     // raw conv fp16; -65504 = outside
    const int tid = threadIdx.x;
    int bi = blockIdx.x;
    const int th = bi & 7;  bi >>= 3;
    const int tt = bi % 63;
    const int b  = bi / 63;
    const int t0 = tt * 16, h0 = th * 64;

    for (int i = tid; i < 23 * 76; i += 320) {
        const int r = i / 76, cc = i % 76;
        const int gt = t0 - 4 + r, gh = h0 - 4 + cc;
        _Float16 val = (_Float16)0.f;   // conv zero-padding
        if (gt >= 0 && gt < T_ && gh >= 0 && gh < H_)
            val = X[((size_t)b * T_ + gt) * H_ + gh];
        in_s[r][cc] = val;
    }
    __syncthreads();

    // conv phase: 18 pt x 17 ph-groups = 306 tasks, one per thread
    if (tid < 306) {
        const int pt = tid / 17;        // conv row: ct = t0 - 1 + pt
        const int co = (tid % 17) * 4;  // conv col offset (co % 4 == 0)

        const int ct = t0 - 1 + pt;
        const bool rok = (ct >= 0) && (ct < T_);
        const int chb = h0 - 1 + co;
        const bool ok0 = rok && (chb + 0 >= 0) && (chb + 0 < H_);
        const bool ok1 = rok && (chb + 1 >= 0) && (chb + 1 < H_);
        const bool ok2 = rok && (chb + 2 >= 0) && (chb + 2 < H_);
        const bool ok3 = rok && (chb + 3 >= 0) && (chb + 3 < H_);

        unsigned acc0[9], acc1[9];      // packed (q0,q1) and (q2,q3), fp16 pairs
        #pragma unroll
        for (int k = 0; k < 9; ++k) { acc0[k] = 0u; acc1[k] = 0u; }

        #pragma unroll 1
        for (int ii = 0; ii < 6; ++ii) {
            const unsigned int* rw = (const unsigned int*)&in_s[pt + ii][co];  // 8-B aligned
            const uint2 a01 = *(const uint2*)(rw);
            const uint2 a23 = *(const uint2*)(rw + 2);
            const unsigned int A0 = a01.x, A1v = a01.y, A2 = a23.x, A3v = a23.y;
            const unsigned int A4 = rw[4];
            // misaligned pairs (1 instr each): M[i] = halves(co+2i+1, co+2i+2)
            const unsigned int M0 = __builtin_amdgcn_alignbit(A1v, A0, 16);
            const unsigned int M1 = __builtin_amdgcn_alignbit(A2, A1v, 16);
            const unsigned int M2 = __builtin_amdgcn_alignbit(A3v, A2, 16);
            const unsigned int M3 = __builtin_amdgcn_alignbit(A4, A3v, 16);

            const unsigned int* wt = ckp + ii * 6;   // + k*36 + J, wave-uniform (SGPR)
            #pragma unroll
            for (int k = 0; k < 9; ++k) {
                const unsigned int* wk = wt + k * 36;
                pk_fma_acc(acc0[k], wk[0], A0);   pk_fma_acc(acc1[k], wk[0], A1v);  // J=0
                pk_fma_acc(acc0[k], wk[1], M0);   pk_fma_acc(acc1[k], wk[1], M1);   // J=1
                pk_fma_acc(acc0[k], wk[2], A1v);  pk_fma_acc(acc1[k], wk[2], A2);   // J=2
                pk_fma_acc(acc0[k], wk[3], M1);   pk_fma_acc(acc1[k], wk[3], M2);   // J=3
                pk_fma_acc(acc0[k], wk[4], A2);   pk_fma_acc(acc1[k], wk[4], A3v);  // J=4
                pk_fma_acc(acc0[k], wk[5], M2);   pk_fma_acc(acc1[k], wk[5], M3);   // J=5
            }
        }

        const _Float16 NEG = (_Float16)(-65504.f);
        #pragma unroll
        for (int k = 0; k < 9; ++k) {
            const h2 pa = __builtin_bit_cast(h2, acc0[k]);
            const h2 pb = __builtin_bit_cast(h2, acc1[k]);
            half4 o;
            o[0] = ok0 ? pa[0] : NEG;
            o[1] = ok1 ? pa[1] : NEG;
            o[2] = ok2 ? pb[0] : NEG;
            o[3] = ok3 ? pb[1] : NEG;
            *(half4*)(&cv[k][pt][co]) = o;
        }
    }
    __syncthreads();

    // pool phase: 16 pt x 16 ph-groups of 4 = 256 tasks; vertical-first packed
    // max, then horizontal; bias+tanh in fp32 on the 4 pooled values only.
    if (tid < 256) {
        const int pt = tid >> 4;
        const int gt = t0 + pt;
        if (gt < T_) {
            const int ph = (tid & 15) * 4;
            _Float16* dst = A3 + ((size_t)b * T_ + gt) * KHID + (h0 + ph);
            #pragma unroll
            for (int k = 0; k < 9; ++k) {
                const unsigned* c0 = (const unsigned*)&cv[k][pt + 0][ph];
                const unsigned* c1 = (const unsigned*)&cv[k][pt + 1][ph];
                const unsigned* c2 = (const unsigned*)&cv[k][pt + 2][ph];
                const uint2 x0 = *(const uint2*)c0;  const unsigned y0 = c0[2];
                const uint2 x1 = *(const uint2*)c1;  const unsigned y1 = c1[2];
                const uint2 x2 = *(const uint2*)c2;  const unsigned y2 = c2[2];
                // vertical max (element-wise over 3 rows)
                const unsigned VA = pk_max(pk_max(x0.x, x1.x), x2.x);  // (u0,u1)
                const unsigned VB = pk_max(pk_max(x0.y, x1.y), x2.y);  // (u2,u3)
                const unsigned VC = pk_max(pk_max(y0,   y1),   y2);    // (u4,u5)
                // horizontal 3-window max on the vertical result
                const unsigned m12 = __builtin_amdgcn_alignbit(VB, VA, 16);  // (u1,u2)
                const unsigned m34 = __builtin_amdgcn_alignbit(VC, VB, 16);  // (u3,u4)
                const unsigned q01 = pk_max(pk_max(VA, m12), VB);
                const unsigned q23 = pk_max(pk_max(VB, m34), VC);
                const h2 qa = __builtin_bit_cast(h2, q01);
                const h2 qb = __builtin_bit_cast(h2, q23);
                const float bk = cb[k];
                half4 o;
                o[0] = (_Float16)tanh_fast((float)qa[0] + bk);
                o[1] = (_Float16)tanh_fast((float)qa[1] + bk);
                o[2] = (_Float16)tanh_fast((float)qb[0] + bk);
                o[3] = (_Float16)tanh_fast((float)qb[1] + bk);
                *(half4*)(dst + (size_t)k * 512) = o;
            }
        }
    }
}

// ---------------------------------------------------------------------------
extern "C" void kernel_launch(void* const* d_in, const int* in_sizes, int n_in,
                              void* d_out, int out_size, void* d_ws, size_t ws_size,
                              hipStream_t stream) {
    const float* inputs = (const float*)d_in[0];
    const float* W_in   = (const float*)d_in[1];
    const float* b_in   = (const float*)d_in[2];
    const float* W_rnn  = (const float*)d_in[3];
    const float* v_rnn  = (const float*)d_in[4];
    const float* b_rnn  = (const float*)d_in[5];
    const float* conv_k = (const float*)d_in[6];
    const float* conv_b = (const float*)d_in[7];
    const float* W_out  = (const float*)d_in[8];
    const float* b_out  = (const float*)d_in[9];
    float* out = (float*)d_out;

    char* ws = (char*)d_ws;
    size_t off = 0;
    auto take = [&](size_t bytes) -> char* {
        off = (off + 255) & ~(size_t)255;
        char* p = ws + off;
        off += bytes;
        return p;
    };
    // W3T first so it survives; A1..U form a dead span at G3 time for Cp alias.
    _Float16* W3T  = (_Float16*)take((size_t)NOUT * KHID * 2);  // W_out[:,257:514)^T, K-permuted
    _Float16* A1   = (_Float16*)take((size_t)M_ * FEATP * 2);   // inputs fp16, padded (dead after G1)
    _Float16* W1T  = (_Float16*)take((size_t)H_ * FEATP * 2);   // W_in^T
    _Float16* W2T0 = (_Float16*)take((size_t)H3 * H_ * 2);      // W_rnn[0]^T
    _Float16* W2T1 = (_Float16*)take((size_t)H3 * H_ * 2);      // W_rnn[1]^T (contiguous after W2T0)
    _Float16* X0   = (_Float16*)take((size_t)M_ * H_ * 2);      // tanh(G1); scan1 output (X2)
    _Float16* X1   = (_Float16*)take((size_t)M_ * H_ * 2);      // scan0 output
    _Float16* U    = (_Float16*)take(3 * (size_t)M_ * 512 * 2); // SoA U planes (xt,fp,rp)
    _Float16* A3   = (_Float16*)take((size_t)M_ * KHID * 2);    // pooled conv, k-major (k*512+h)
    unsigned int* ckp = (unsigned int*)take(9 * 36 * 4);        // packed dup'd fp16 conv weights
    // Split-K partials alias the dead A1..U span (65.8 MB < 111 MB span; U dead after scan1):
    float* Cp = (float*)A1;
    _Float16* X2 = X0;  // X0 dead after G2-layer0+scan0 -> reuse for scan1 output

    // --- weight/input preprocessing (fp32 -> fp16, transpose to NxK) ---
    {
        size_t n = (size_t)M_ * FEATP;
        convert_inputs<<<dim3((unsigned)((n + 255) / 256)), 256, 0, stream>>>(inputs, A1, conv_k, ckp);
    }
    transpose_w<<<dim3(25, 16), 256, 0, stream>>>(W_in, W1T, FEAT, H_, H_, 0, FEATP, 0, 0, 0);
    transpose_w<<<dim3(16, 48, 2), 256, 0, stream>>>(W_rnn, W2T0, H_, H3, H3, 0, H_, 0,
                                                     (size_t)H_ * H3, (size_t)H3 * H_);
    transpose_w<<<dim3(144, 9), 256, 0, stream>>>(W_out, W3T, KHID, NOUT, FEAT, 257, KHID, 1, 0, 0);

    // --- G1: X0 = tanh(inputs @ W_in + b_in) ---
    gemm_kernel<0, 0><<<dim3(125, 4), 256, 0, stream>>>(A1, W1T, FEATP, 25, H_, X0, nullptr, H_, b_in);

    // --- SRU layer 0: U-GEMM (SoA) -> LDS-staged scan (reads planes directly) ---
    gemm_kernel<1, 0><<<dim3(125, 12), 256, 0, stream>>>(X0, W2T0, H_, 16, H3, U, nullptr, 0, nullptr);
    sru_scan<<<dim3(128), 64, 0, stream>>>(U, X0, X1, v_rnn, b_rnn);

    // --- SRU layer 1 ---
    gemm_kernel<1, 0><<<dim3(125, 12), 256, 0, stream>>>(X1, W2T1, H_, 16, H3, U, nullptr, 0, nullptr);
    sru_scan<<<dim3(128), 64, 0, stream>>>(U, X1, X2, v_rnn + 1024, b_rnn + 1024);

    // --- conv + maxpool + bias + tanh fused, producing final-GEMM A matrix ---
    conv_pool<<<dim3(16 * 63 * 8), 320, 0, stream>>>(X2, ckp, conv_b, A3);

    // --- G3 split-K (ragged-N, KSLICES=4 -> 1500 blocks): Cp[z] = A3 @ W3T, then reduce ---
    gemm_kernel<3, 1><<<dim3(125, 3, KSLICES), 256, 0, stream>>>(A3, W3T, KHID, 144 / KSLICES, NOUT, nullptr, Cp, 0, nullptr);
    {
        const unsigned nred = (unsigned)(((size_t)M_ * NOUT + 255) / 256);
        reduce_out<<<dim3(nred), 256, 0, stream>>>(Cp, b_out + 257, inputs, out);
    }
}

// Round 14
// 687.322 us; speedup vs baseline: 1.0935x; 1.0242x over previous
//
#include <hip/hip_runtime.h>
#include <hip/hip_bf16.h>

// Problem constants
#define B_    16
#define T_    1000
#define FEAT  771
#define FEATP 800      // 771 padded to 25*32 (exact BK multiple -> guard-free GEMM)
#define H_    512
#define H3    1536
#define KN_   9
#define KHID  4608     // H*KN
#define M_    16000    // B*T
#define NOUT  257      // output column slice [257:514)
#define KSLICES 2      // split-K for the final GEMM (empirical optimum: r8/r13 A/B)

typedef _Float16 half8 __attribute__((ext_vector_type(8)));
typedef _Float16 half4 __attribute__((ext_vector_type(4)));
typedef _Float16 half2v __attribute__((ext_vector_type(2)));
typedef _Float16 h2 __attribute__((ext_vector_type(2)));
typedef float    floatx4 __attribute__((ext_vector_type(4)));

// tanh(z) = 1 - 2/(1+e^{2z})  — saturates correctly at +/-inf, no NaN
__device__ inline float tanh_fast(float z) {
    return 1.0f - 2.0f / (1.0f + __expf(2.0f * z));
}
__device__ inline float sigmoid_fast(float z) {
    return 1.0f / (1.0f + __expf(-z));
}

// async global->LDS, 16B per lane; LDS dst must be wave-uniform base
__device__ inline void gload16(const _Float16* g, _Float16* l) {
    __builtin_amdgcn_global_load_lds(
        (const __attribute__((address_space(1))) void*)g,
        (__attribute__((address_space(3))) void*)l, 16, 0, 0);
}

// Guaranteed packed fp16 ops; w is wave-uniform (SGPR src0).
__device__ inline void pk_fma_acc(unsigned& acc, unsigned w, unsigned x) {
    asm("v_pk_fma_f16 %0, %1, %2, %0" : "+v"(acc) : "s"(w), "v"(x));
}
__device__ inline unsigned pk_max(unsigned a, unsigned b) {
    unsigned d;
    asm("v_pk_max_f16 %0, %1, %2" : "=v"(d) : "v"(a), "v"(b));
    return d;
}

// ---------------------------------------------------------------------------
// fp32 -> fp16 convert of inputs, padding rows 771 -> 800 with zeros.
// Block 0 additionally packs ALL 324 conv weights (stride loop).
__global__ void convert_inputs(const float* __restrict__ in, _Float16* __restrict__ A1,
                               const float* __restrict__ ck, unsigned int* __restrict__ ckp) {
    if (blockIdx.x == 0) {
        for (int j = threadIdx.x; j < 9 * 36; j += 256) {
            const _Float16 w = (_Float16)ck[j];
            const unsigned short u = __builtin_bit_cast(unsigned short, w);
            ckp[j] = ((unsigned int)u << 16) | u;
        }
    }
    size_t i = (size_t)blockIdx.x * 256 + threadIdx.x;
    if (i >= (size_t)M_ * FEATP) return;
    size_t r = i / FEATP;
    int   cc = (int)(i % FEATP);
    A1[i] = (cc < FEAT) ? (_Float16)in[r * FEAT + cc] : (_Float16)0.f;
}

// ---------------------------------------------------------------------------
// LDS-tiled transpose+convert: Wt[n*Kp + kidx] = (k<K) ? W[k*ldw + coloff + n] : 0
// perm9: kidx = (k%9)*512 + k/9  (k-major planes for the conv output layout)
// blockIdx.z strides src by zsrc and dst by zdst (batched transposes).
__global__ __launch_bounds__(256) void transpose_w(
    const float* __restrict__ W, _Float16* __restrict__ Wt,
    int K, int N, int ldw, int coloff, int Kp, int perm9,
    size_t zsrc, size_t zdst)
{
    W  += (size_t)blockIdx.z * zsrc;
    Wt += (size_t)blockIdx.z * zdst;
    __shared__ float tile[32][33];
    const int kb = blockIdx.x * 32;
    const int nb = blockIdx.y * 32;
    const int tx = threadIdx.x & 31;
    const int ty = threadIdx.x >> 5;   // 0..7
    #pragma unroll
    for (int r = ty; r < 32; r += 8) {
        const int k = kb + r, n = nb + tx;
        tile[r][tx] = (k < K && n < N) ? W[(size_t)k * ldw + coloff + n] : 0.f;
    }
    __syncthreads();
    #pragma unroll
    for (int r = ty; r < 32; r += 8) {
        const int n = nb + r, k = kb + tx;
        if (n < N && k < Kp) {
            size_t kidx = (size_t)k;
            if (perm9) kidx = (size_t)(k % 9) * 512 + (size_t)(k / 9);
            Wt[(size_t)n * Kp + kidx] = (_Float16)tile[tx][r];
        }
    }
}

// ---------------------------------------------------------------------------
// Tiled fp16 MFMA GEMM: C[M x N] = A[M x Kp] * Bt[N x Kp]^T, fp32 accumulate.
// 128x128 block tile, BK=32, 4 waves (2x2), each wave 4x4 of 16x16x32 MFMA.
// 2-phase prefetch: double-buffered LDS, tile k+1 staged via global_load_lds
// BEFORE computing tile k; one vmcnt(0)+raw-barrier per K-step.
// RAG=1: ragged-N wave-uniform guards (G3's last n-tile: 1/128 cols live).
template <int EPI, int RAG>
__global__ __launch_bounds__(256) void gemm_kernel(
    const _Float16* __restrict__ A, const _Float16* __restrict__ Bt,
    int Kp, int nk, int Nb,
    _Float16* __restrict__ Ch, float* __restrict__ Cf, int ldc,
    const float* __restrict__ bias)
{
    __shared__ __align__(16) _Float16 As[2][128][32];
    __shared__ __align__(16) _Float16 Bs[2][128][32];

    const int tid  = threadIdx.x;
    const int m0   = blockIdx.x * 128;
    const int n0   = blockIdx.y * 128;
    const int koff = blockIdx.z * (nk << 5);   // K-slice origin
    const int wave = tid >> 6;
    const int lane = tid & 63;
    const int wr   = (wave >> 1) << 6;   // wave row offset (0/64)
    const int wc   = (wave & 1) << 6;    // wave col offset (0/64)
    const int lrow = lane & 15;
    const int lq   = lane >> 4;          // 0..3
    const bool waveAlive = !RAG || (n0 + wc < Nb);

    // staging: wave w stages rows [w*32, w*32+32), 2 instrs per matrix
    const int srow0  = wave * 32 + (lane >> 2);   // rows for instr 0
    const int schunk = (lane & 3) * 8;            // halves within row
    const _Float16* aSrc = A  + (size_t)(m0 + srow0) * Kp + koff + schunk;
    const _Float16* bSrc = Bt + (size_t)(n0 + srow0) * Kp + koff + schunk;
    const size_t rstep = (size_t)16 * Kp;

    floatx4 acc[4][4];
    #pragma unroll
    for (int i = 0; i < 4; ++i)
        #pragma unroll
        for (int j = 0; j < 4; ++j)
            #pragma unroll
            for (int r = 0; r < 4; ++r) acc[i][j][r] = 0.f;

    // prologue: stage tile 0 into buffer 0
    gload16(aSrc,         &As[0][wave * 32][0]);
    gload16(aSrc + rstep, &As[0][wave * 32 + 16][0]);
    gload16(bSrc,         &Bs[0][wave * 32][0]);
    gload16(bSrc + rstep, &Bs[0][wave * 32 + 16][0]);
    asm volatile("s_waitcnt vmcnt(0)" ::: "memory");
    __builtin_amdgcn_s_barrier();

    for (int kc = 0; kc < nk; ++kc) {
        const int cur = kc & 1;
        if (kc + 1 < nk) {   // prefetch next tile into the other buffer
            const _Float16* a2 = aSrc + (size_t)(kc + 1) * 32;
            const _Float16* b2 = bSrc + (size_t)(kc + 1) * 32;
            gload16(a2,         &As[cur ^ 1][wave * 32][0]);
            gload16(a2 + rstep, &As[cur ^ 1][wave * 32 + 16][0]);
            gload16(b2,         &Bs[cur ^ 1][wave * 32][0]);
            gload16(b2 + rstep, &Bs[cur ^ 1][wave * 32 + 16][0]);
        }

        if (waveAlive) {
            half8 af[4], bfr[4];
            #pragma unroll
            for (int i = 0; i < 4; ++i) af[i] = *(const half8*)(&As[cur][wr + i * 16 + lrow][lq * 8]);
            #pragma unroll
            for (int j = 0; j < 4; ++j) {
                if (RAG && n0 + wc + j * 16 >= Nb) continue;
                bfr[j] = *(const half8*)(&Bs[cur][wc + j * 16 + lrow][lq * 8]);
            }
            #pragma unroll
            for (int i = 0; i < 4; ++i)
                #pragma unroll
                for (int j = 0; j < 4; ++j) {
                    if (RAG && n0 + wc + j * 16 >= Nb) continue;
                    acc[i][j] = __builtin_amdgcn_mfma_f32_16x16x32_f16(af[i], bfr[j], acc[i][j], 0, 0, 0);
                }
        }

        if (kc + 1 < nk) {
            asm volatile("s_waitcnt vmcnt(0)" ::: "memory");
            __builtin_amdgcn_s_barrier();
        }
    }

    // Epilogue: C/D layout col=lane&15, row=quad*4+reg
    #pragma unroll
    for (int j = 0; j < 4; ++j) {
        const int col = n0 + wc + j * 16 + lrow;
        if (col >= Nb) continue;
        #pragma unroll
        for (int i = 0; i < 4; ++i) {
            #pragma unroll
            for (int r = 0; r < 4; ++r) {
                const int row = m0 + wr + i * 16 + lq * 4 + r;
                float v = acc[i][j][r];
                if constexpr (EPI == 0) {
                    float z = v + bias[col];
                    Ch[(size_t)row * ldc + col] = (_Float16)tanh_fast(z);
                } else if constexpr (EPI == 1) {
                    Ch[(size_t)(col >> 9) * ((size_t)M_ * 512) + (size_t)row * 512 + (col & 511)] = (_Float16)v;
                } else {
                    Cf[(size_t)blockIdx.z * M_ * NOUT + (size_t)row * NOUT + col] = v;
                }
            }
        }
    }
}

// ---------------------------------------------------------------------------
// Split-K reduction + sigmoid epilogue for the final GEMM (KSLICES=2).
__global__ __launch_bounds__(256) void reduce_out(
    const float* __restrict__ Cp, const float* __restrict__ bias,
    const float* __restrict__ aux, float* __restrict__ out)
{
    const size_t i = (size_t)blockIdx.x * 256 + threadIdx.x;
    if (i >= (size_t)M_ * NOUT) return;
    const int row = (int)(i / NOUT);
    const int col = (int)(i % NOUT);
    float s = Cp[i] + Cp[i + (size_t)M_ * NOUT];
    out[i] = sigmoid_fast(s + bias[col]) * aux[(size_t)row * FEAT + 257 + col];
}

// ---------------------------------------------------------------------------
// SRU scan reading SoA U planes + X directly via LDS double-buffer staging.
// Each 40-step buffer staged with exactly 20 global_load_lds; double-buffered;
// counted vmcnt(20) keeps next buffer's loads in flight under the compute.
__global__ __launch_bounds__(64) void sru_scan(
    const _Float16* __restrict__ U,   // 3 planes [M][512] (xt, fp, rp)
    const _Float16* __restrict__ X,   // [M][512] layer input
    _Float16* __restrict__ Xout,
    const float* __restrict__ v, const float* __restrict__ bg)
{
    __shared__ __align__(16) _Float16 lds[2][4][40][64];   // 40 KiB
    const int tid = threadIdx.x;
    const int b   = blockIdx.x >> 3;
    const int h0  = (blockIdx.x & 7) << 6;
    const int h   = h0 + tid;
    const float vf = v[h],       vr = v[512 + h];
    const float bf = bg[h],      br = bg[512 + h];

    const _Float16* plane0 = U;
    const _Float16* plane1 = U + (size_t)M_ * 512;
    const _Float16* plane2 = U + 2 * (size_t)M_ * 512;
    const _Float16* plane3 = X;

    const int lrow = tid >> 3;        // 0..7: t sub-row within a 1KB chunk
    const int lcol = (tid & 7) * 8;   // halves within row (16 B per lane)

    _Float16* ox = Xout + (size_t)b * T_ * 512 + h;

    // refill buffer bufi with t-rows [t0, t0+40)
    auto refill = [&](int bufi, int t0) {
        const size_t rbase = (size_t)(b * T_ + t0 + lrow) * 512 + h0 + lcol;
        #pragma unroll
        for (int j = 0; j < 5; ++j) {
            const size_t o = rbase + (size_t)(8 * j) * 512;
            gload16(plane0 + o, &lds[bufi][0][8 * j][0]);
            gload16(plane1 + o, &lds[bufi][1][8 * j][0]);
            gload16(plane2 + o, &lds[bufi][2][8 * j][0]);
            gload16(plane3 + o, &lds[bufi][3][8 * j][0]);
        }
    };

    refill(0, 0);
    float c = 0.f;
    int cur = 0;
    for (int tb = 0; tb < 25; ++tb) {
        const int t0 = tb * 40;
        if (tb + 1 < 25) {
            refill(cur ^ 1, t0 + 40);
            asm volatile("s_waitcnt vmcnt(20)" ::: "memory");
        } else {
            asm volatile("s_waitcnt vmcnt(0)" ::: "memory");
        }
        __builtin_amdgcn_sched_barrier(0);
        #pragma unroll
        for (int j = 0; j < 40; ++j) {
            const float xt = (float)lds[cur][0][j][tid];
            const float fp = (float)lds[cur][1][j][tid];
            const float rp = (float)lds[cur][2][j][tid];
            const float x  = (float)lds[cur][3][j][tid];
            const float f  = sigmoid_fast(fp + vf * c + bf);
            const float r  = sigmoid_fast(rp + vr * c + br);
            const float cn = f * c + (1.0f - f) * xt;
            const float hO = r * cn + (1.0f - r) * x;
            ox[(size_t)(t0 + j) * 512] = (_Float16)hO;
            c = cn;
        }
        cur ^= 1;
    }
}

// ---------------------------------------------------------------------------
// Fused conv6x6(asym pad 3,2) + maxpool3x3(pad 1) + bias + tanh.
// EXACT r8 structure (best measured: 134.5 µs) — 320 threads, packed fp16
// inline asm, vertical-first pool, tanh after pool, k-major output.
#define CVW 76   // cv row width (halves)

__global__ __launch_bounds__(320) void conv_pool(
    const _Float16* __restrict__ X, const unsigned int* __restrict__ ckp,
    const float* __restrict__ cb, _Float16* __restrict__ A3)
{
    __shared__ __align__(16) _Float16 in_s[23][80];       // fp16, rows padded to 80
    __shared__ __align__(16) _Float16 cv[9][18][CVW];     // raw conv fp16; -65504 = outside
    const int tid = threadIdx.x;
    int bi = blockIdx.x;
    const int th = bi & 7;  bi >>= 3;
    const int tt = bi % 63;
    const int b  = bi / 63;
    const int t0 = tt * 16, h0 = th * 64;

    for (int i = tid; i < 23 * 76; i += 320) {
        const int r = i / 76, cc = i % 76;
        const int gt = t0 - 4 + r, gh = h0 - 4 + cc;
        _Float16 val = (_Float16)0.f;   // conv zero-padding
        if (gt >= 0 && gt < T_ && gh >= 0 && gh < H_)
            val = X[((size_t)b * T_ + gt) * H_ + gh];
        in_s[r][cc] = val;
    }
    __syncthreads();

    // conv phase: 18 pt x 17 ph-groups = 306 tasks, one per thread
    if (tid < 306) {
        const int pt = tid / 17;        // conv row: ct = t0 - 1 + pt
        const int co = (tid % 17) * 4;  // conv col offset (co % 4 == 0)

        const int ct = t0 - 1 + pt;
        const bool rok = (ct >= 0) && (ct < T_);
        const int chb = h0 - 1 + co;
        const bool ok0 = rok && (chb + 0 >= 0) && (chb + 0 < H_);
        const bool ok1 = rok && (chb + 1 >= 0) && (chb + 1 < H_);
        const bool ok2 = rok && (chb + 2 >= 0) && (chb + 2 < H_);
        const bool ok3 = rok && (chb + 3 >= 0) && (chb + 3 < H_);

        unsigned acc0[9], acc1[9];      // packed (q0,q1) and (q2,q3), fp16 pairs
        #pragma unroll
        for (int k = 0; k < 9; ++k) { acc0[k] = 0u; acc1[k] = 0u; }

        #pragma unroll 1
        for (int ii = 0; ii < 6; ++ii) {
            const unsigned int* rw = (const unsigned int*)&in_s[pt + ii][co];  // 8-B aligned
            const uint2 a01 = *(const uint2*)(rw);
            const uint2 a23 = *(const uint2*)(rw + 2);
            const unsigned int A0 = a01.x, A1v = a01.y, A2 = a23.x, A3v = a23.y;
            const unsigned int A4 = rw[4];
            // misaligned pairs (1 instr each): M[i] = halves(co+2i+1, co+2i+2)
            const unsigned int M0 = __builtin_amdgcn_alignbit(A1v, A0, 16);
            const unsigned int M1 = __builtin_amdgcn_alignbit(A2, A1v, 16);
            const unsigned int M2 = __builtin_amdgcn_alignbit(A3v, A2, 16);
            const unsigned int M3 = __builtin_amdgcn_alignbit(A4, A3v, 16);

            const unsigned int* wt = ckp + ii * 6;   // + k*36 + J, wave-uniform (SGPR)
            #pragma unroll
            for (int k = 0; k < 9; ++k) {
                const unsigned int* wk = wt + k * 36;
                pk_fma_acc(acc0[k], wk[0], A0);   pk_fma_acc(acc1[k], wk[0], A1v);  // J=0
                pk_fma_acc(acc0[k], wk[1], M0);   pk_fma_acc(acc1[k], wk[1], M1);   // J=1
                pk_fma_acc(acc0[k], wk[2], A1v);  pk_fma_acc(acc1[k], wk[2], A2);   // J=2
                pk_fma_acc(acc0[k], wk[3], M1);   pk_fma_acc(acc1[k], wk[3], M2);   // J=3
                pk_fma_acc(acc0[k], wk[4], A2);   pk_fma_acc(acc1[k], wk[4], A3v);  // J=4
                pk_fma_acc(acc0[k], wk[5], M2);   pk_fma_acc(acc1[k], wk[5], M3);   // J=5
            }
        }

        const _Float16 NEG = (_Float16)(-65504.f);
        #pragma unroll
        for (int k = 0; k < 9; ++k) {
            const h2 pa = __builtin_bit_cast(h2, acc0[k]);
            const h2 pb = __builtin_bit_cast(h2, acc1[k]);
            half4 o;
            o[0] = ok0 ? pa[0] : NEG;
            o[1] = ok1 ? pa[1] : NEG;
            o[2] = ok2 ? pb[0] : NEG;
            o[3] = ok3 ? pb[1] : NEG;
            *(half4*)(&cv[k][pt][co]) = o;
        }
    }
    __syncthreads();

    // pool phase: 16 pt x 16 ph-groups of 4 = 256 tasks; vertical-first packed
    // max, then horizontal; bias+tanh in fp32 on the 4 pooled values only.
    if (tid < 256) {
        const int pt = tid >> 4;
        const int gt = t0 + pt;
        if (gt < T_) {
            const int ph = (tid & 15) * 4;
            _Float16* dst = A3 + ((size_t)b * T_ + gt) * KHID + (h0 + ph);
            #pragma unroll
            for (int k = 0; k < 9; ++k) {
                const unsigned* c0 = (const unsigned*)&cv[k][pt + 0][ph];
                const unsigned* c1 = (const unsigned*)&cv[k][pt + 1][ph];
                const unsigned* c2 = (const unsigned*)&cv[k][pt + 2][ph];
                const uint2 x0 = *(const uint2*)c0;  const unsigned y0 = c0[2];
                const uint2 x1 = *(const uint2*)c1;  const unsigned y1 = c1[2];
                const uint2 x2 = *(const uint2*)c2;  const unsigned y2 = c2[2];
                // vertical max (element-wise over 3 rows)
                const unsigned VA = pk_max(pk_max(x0.x, x1.x), x2.x);  // (u0,u1)
                const unsigned VB = pk_max(pk_max(x0.y, x1.y), x2.y);  // (u2,u3)
                const unsigned VC = pk_max(pk_max(y0,   y1),   y2);    // (u4,u5)
                // horizontal 3-window max on the vertical result
                const unsigned m12 = __builtin_amdgcn_alignbit(VB, VA, 16);  // (u1,u2)
                const unsigned m34 = __builtin_amdgcn_alignbit(VC, VB, 16);  // (u3,u4)
                const unsigned q01 = pk_max(pk_max(VA, m12), VB);
                const unsigned q23 = pk_max(pk_max(VB, m34), VC);
                const h2 qa = __builtin_bit_cast(h2, q01);
                const h2 qb = __builtin_bit_cast(h2, q23);
                const float bk = cb[k];
                half4 o;
                o[0] = (_Float16)tanh_fast((float)qa[0] + bk);
                o[1] = (_Float16)tanh_fast((float)qa[1] + bk);
                o[2] = (_Float16)tanh_fast((float)qb[0] + bk);
                o[3] = (_Float16)tanh_fast((float)qb[1] + bk);
                *(half4*)(dst + (size_t)k * 512) = o;
            }
        }
    }
}

// ---------------------------------------------------------------------------
extern "C" void kernel_launch(void* const* d_in, const int* in_sizes, int n_in,
                              void* d_out, int out_size, void* d_ws, size_t ws_size,
                              hipStream_t stream) {
    const float* inputs = (const float*)d_in[0];
    const float* W_in   = (const float*)d_in[1];
    const float* b_in   = (const float*)d_in[2];
    const float* W_rnn  = (const float*)d_in[3];
    const float* v_rnn  = (const float*)d_in[4];
    const float* b_rnn  = (const float*)d_in[5];
    const float* conv_k = (const float*)d_in[6];
    const float* conv_b = (const float*)d_in[7];
    const float* W_out  = (const float*)d_in[8];
    const float* b_out  = (const float*)d_in[9];
    float* out = (float*)d_out;

    char* ws = (char*)d_ws;
    size_t off = 0;
    auto take = [&](size_t bytes) -> char* {
        off = (off + 255) & ~(size_t)255;
        char* p = ws + off;
        off += bytes;
        return p;
    };
    // W3T first so it survives; A1..X1 form a dead span at G3 time for Cp alias.
    _Float16* W3T  = (_Float16*)take((size_t)NOUT * KHID * 2);  // W_out[:,257:514)^T, K-permuted
    _Float16* A1   = (_Float16*)take((size_t)M_ * FEATP * 2);   // inputs fp16, padded (dead after G1)
    _Float16* W1T  = (_Float16*)take((size_t)H_ * FEATP * 2);   // W_in^T
    _Float16* W2T0 = (_Float16*)take((size_t)H3 * H_ * 2);      // W_rnn[0]^T
    _Float16* W2T1 = (_Float16*)take((size_t)H3 * H_ * 2);      // W_rnn[1]^T (contiguous after W2T0)
    _Float16* X0   = (_Float16*)take((size_t)M_ * H_ * 2);      // tanh(G1); scan1 output (X2)
    _Float16* X1   = (_Float16*)take((size_t)M_ * H_ * 2);      // scan0 output
    _Float16* U    = (_Float16*)take(3 * (size_t)M_ * 512 * 2); // SoA U planes (xt,fp,rp)
    _Float16* A3   = (_Float16*)take((size_t)M_ * KHID * 2);    // pooled conv, k-major (k*512+h)
    unsigned int* ckp = (unsigned int*)take(9 * 36 * 4);        // packed dup'd fp16 conv weights
    // Split-K partials alias the dead A1..X1 span (32.9 MB < 62.4 MB span):
    float* Cp = (float*)A1;
    _Float16* X2 = X0;  // X0 dead after G2-layer0+scan0 -> reuse for scan1 output

    // --- weight/input preprocessing (fp32 -> fp16, transpose to NxK) ---
    {
        size_t n = (size_t)M_ * FEATP;
        convert_inputs<<<dim3((unsigned)((n + 255) / 256)), 256, 0, stream>>>(inputs, A1, conv_k, ckp);
    }
    transpose_w<<<dim3(25, 16), 256, 0, stream>>>(W_in, W1T, FEAT, H_, H_, 0, FEATP, 0, 0, 0);
    transpose_w<<<dim3(16, 48, 2), 256, 0, stream>>>(W_rnn, W2T0, H_, H3, H3, 0, H_, 0,
                                                     (size_t)H_ * H3, (size_t)H3 * H_);
    transpose_w<<<dim3(144, 9), 256, 0, stream>>>(W_out, W3T, KHID, NOUT, FEAT, 257, KHID, 1, 0, 0);

    // --- G1: X0 = tanh(inputs @ W_in + b_in) ---
    gemm_kernel<0, 0><<<dim3(125, 4), 256, 0, stream>>>(A1, W1T, FEATP, 25, H_, X0, nullptr, H_, b_in);

    // --- SRU layer 0: U-GEMM (SoA) -> LDS-staged scan (reads planes directly) ---
    gemm_kernel<1, 0><<<dim3(125, 12), 256, 0, stream>>>(X0, W2T0, H_, 16, H3, U, nullptr, 0, nullptr);
    sru_scan<<<dim3(128), 64, 0, stream>>>(U, X0, X1, v_rnn, b_rnn);

    // --- SRU layer 1 ---
    gemm_kernel<1, 0><<<dim3(125, 12), 256, 0, stream>>>(X1, W2T1, H_, 16, H3, U, nullptr, 0, nullptr);
    sru_scan<<<dim3(128), 64, 0, stream>>>(U, X1, X2, v_rnn + 1024, b_rnn + 1024);

    // --- conv + maxpool + bias + tanh fused, producing final-GEMM A matrix ---
    conv_pool<<<dim3(16 * 63 * 8), 320, 0, stream>>>(X2, ckp, conv_b, A3);

    // --- G3 split-K (ragged-N, KSLICES=2): Cp[z] = A3 @ W3T, then reduce+sigmoid+mask ---
    gemm_kernel<3, 1><<<dim3(125, 3, KSLICES), 256, 0, stream>>>(A3, W3T, KHID, 144 / KSLICES, NOUT, nullptr, Cp, 0, nullptr);
    {
        const unsigned nred = (unsigned)(((size_t)M_ * NOUT + 255) / 256);
        reduce_out<<<dim3(nred), 256, 0, stream>>>(Cp, b_out + 257, inputs, out);
    }
}